// Round 3
// baseline (16708.589 us; speedup 1.0000x reference)
//
#include <hip/hip_runtime.h>
#include <math.h>

#define NNODES 50000
#define NEDGES 1600000
#define DIM    128
#define NHID   (NNODES * DIM)      // 6,400,000
#define TPB    256
#define ROWS   32

// ---------------------------------------------------------------------------
// Scatter-add: agg[dst[e]] += h[src[e]]   (segment_sum)
// 32 lanes per edge, one float4 per lane, 4 fp32 global atomics each.
// ---------------------------------------------------------------------------
__global__ __launch_bounds__(TPB) void scatter_add_kernel(
    const float* __restrict__ h, const int* __restrict__ src,
    const int* __restrict__ dst, float* __restrict__ agg)
{
    long tid = (long)blockIdx.x * TPB + threadIdx.x;
    int e = (int)(tid >> 5);
    int c = (int)(tid & 31);
    if (e >= NEDGES) return;
    int s = src[e], d = dst[e];
    float4 v = ((const float4*)(h + (size_t)s * DIM))[c];
    float* o = agg + (size_t)d * DIM + c * 4;
    atomicAdd(o + 0, v.x);
    atomicAdd(o + 1, v.y);
    atomicAdd(o + 2, v.z);
    atomicAdd(o + 3, v.w);
}

// ---------------------------------------------------------------------------
// 128x128 GEMM over row tiles, fused prologue/epilogue.
//   z = (agg ? scale*hin + agg : hin)            [row tile staged in LDS]
//   y = z @ W + bias
//   mode 0: out = y
//   mode 1: out = sigmoid(y)
//   mode 2: out = layernorm(y) * gamma + beta    (per-row, eps=1e-5)
// In-place (out == hin) is safe: each block stages its rows into LDS before
// writing them back, and blocks own disjoint row ranges.
// ---------------------------------------------------------------------------
__global__ __launch_bounds__(TPB) void gemm128_kernel(
    const float* hin, const float* __restrict__ agg,
    const float* __restrict__ eps_ptr, int eps_idx,
    const float* __restrict__ W, const float* __restrict__ bias,
    const float* __restrict__ gamma, const float* __restrict__ beta,
    float* out, int mode)
{
    __shared__ float sW[DIM * DIM];   // 64 KB
    __shared__ float sZ[ROWS * DIM];  // 16 KB  -> 80 KB total, 2 blocks/CU

    {   // load weights once per block
        const float4* Wv = (const float4*)W;
        float4* sWv = (float4*)sW;
        #pragma unroll
        for (int i = 0; i < (DIM * DIM / 4) / TPB; i++)
            sWv[threadIdx.x + i * TPB] = Wv[threadIdx.x + i * TPB];
    }

    float scale = 1.0f;
    if (agg != nullptr) scale = 1.0f + eps_ptr[eps_idx];

    const int tx = threadIdx.x & 31;   // column group: cols 4tx..4tx+3
    const int ty = threadIdx.x >> 5;   // row group: rows ty+8j, j<4

    float4 bv = ((const float4*)bias)[tx];
    float4 gv = make_float4(0, 0, 0, 0), btv = make_float4(0, 0, 0, 0);
    if (mode == 2) { gv = ((const float4*)gamma)[tx]; btv = ((const float4*)beta)[tx]; }

    const int ntiles = (NNODES + ROWS - 1) / ROWS;
    for (int tile = blockIdx.x; tile < ntiles; tile += gridDim.x) {
        const int r0 = tile * ROWS;
        const int nrows = min(ROWS, NNODES - r0);
        __syncthreads();  // protect sZ reuse (and first-iter W load)
        {
            const float4* hv = (const float4*)(hin + (size_t)r0 * DIM);
            float4* sZv = (float4*)sZ;
            const int cnt = nrows * (DIM / 4);
            if (agg != nullptr) {
                const float4* av = (const float4*)(agg + (size_t)r0 * DIM);
                for (int i = threadIdx.x; i < cnt; i += TPB) {
                    float4 hx = hv[i], ax = av[i], z;
                    z.x = fmaf(scale, hx.x, ax.x);
                    z.y = fmaf(scale, hx.y, ax.y);
                    z.z = fmaf(scale, hx.z, ax.z);
                    z.w = fmaf(scale, hx.w, ax.w);
                    sZv[i] = z;
                }
            } else {
                for (int i = threadIdx.x; i < cnt; i += TPB) sZv[i] = hv[i];
            }
        }
        __syncthreads();

        float4 acc[4];
        #pragma unroll
        for (int j = 0; j < 4; j++) acc[j] = make_float4(0, 0, 0, 0);

        const float4* sWv = (const float4*)sW;
        #pragma unroll 4
        for (int k = 0; k < DIM; k++) {
            float4 w4 = sWv[k * (DIM / 4) + tx];
            #pragma unroll
            for (int j = 0; j < 4; j++) {
                float zk = sZ[(ty + 8 * j) * DIM + k];
                acc[j].x = fmaf(zk, w4.x, acc[j].x);
                acc[j].y = fmaf(zk, w4.y, acc[j].y);
                acc[j].z = fmaf(zk, w4.z, acc[j].z);
                acc[j].w = fmaf(zk, w4.w, acc[j].w);
            }
        }

        #pragma unroll
        for (int j = 0; j < 4; j++) {
            int rl = ty + 8 * j;
            float4 v = acc[j];
            v.x += bv.x; v.y += bv.y; v.z += bv.z; v.w += bv.w;
            if (mode == 1) {
                v.x = 1.0f / (1.0f + expf(-v.x));
                v.y = 1.0f / (1.0f + expf(-v.y));
                v.z = 1.0f / (1.0f + expf(-v.z));
                v.w = 1.0f / (1.0f + expf(-v.w));
            } else if (mode == 2) {
                float s1 = v.x + v.y + v.z + v.w;
                float s2 = fmaf(v.x, v.x, fmaf(v.y, v.y, fmaf(v.z, v.z, v.w * v.w)));
                #pragma unroll
                for (int m = 16; m >= 1; m >>= 1) {   // xor<32 stays in tx-half
                    s1 += __shfl_xor(s1, m);
                    s2 += __shfl_xor(s2, m);
                }
                float mean = s1 * (1.0f / DIM);
                float var  = s2 * (1.0f / DIM) - mean * mean;
                float rstd = rsqrtf(var + 1e-5f);
                v.x = fmaf((v.x - mean) * rstd, gv.x, btv.x);
                v.y = fmaf((v.y - mean) * rstd, gv.y, btv.y);
                v.z = fmaf((v.z - mean) * rstd, gv.z, btv.z);
                v.w = fmaf((v.w - mean) * rstd, gv.w, btv.w);
            }
            if (rl < nrows)
                ((float4*)(out + (size_t)(r0 + rl) * DIM))[tx] = v;
        }
    }
}

// ---------------------------------------------------------------------------
// samples = mean_v + eps * std_v with eps = jax.random.normal(key(42)) under
// jax_threefry_partitionable=True (default since jax 0.4.36):
//   per flat element i: 64-bit counter i -> block inputs (hi=0, lo=i);
//   for 32-bit draws, bits = out0 XOR out1  (prng.py: bits1 ^ bits2).
//   Key = (0, 42).
// ---------------------------------------------------------------------------
__device__ __forceinline__ unsigned rotl32(unsigned x, int r) {
    return (x << r) | (x >> (32 - r));
}

__device__ __forceinline__ unsigned threefry_xor(unsigned c0, unsigned c1) {
    const unsigned k0 = 0u, k1 = 42u;
    const unsigned k2 = k0 ^ k1 ^ 0x1BD11BDAu;
    unsigned x0 = c0 + k0;
    unsigned x1 = c1 + k1;
#define TF_ROUND(R) { x0 += x1; x1 = rotl32(x1, R); x1 ^= x0; }
    TF_ROUND(13) TF_ROUND(15) TF_ROUND(26) TF_ROUND(6)
    x0 += k1; x1 += k2 + 1u;
    TF_ROUND(17) TF_ROUND(29) TF_ROUND(16) TF_ROUND(24)
    x0 += k2; x1 += k0 + 2u;
    TF_ROUND(13) TF_ROUND(15) TF_ROUND(26) TF_ROUND(6)
    x0 += k0; x1 += k1 + 3u;
    TF_ROUND(17) TF_ROUND(29) TF_ROUND(16) TF_ROUND(24)
    x0 += k1; x1 += k2 + 4u;
    TF_ROUND(13) TF_ROUND(15) TF_ROUND(26) TF_ROUND(6)
    x0 += k2; x1 += k0 + 5u;
#undef TF_ROUND
    return x0 ^ x1;
}

__device__ __forceinline__ float bits_to_normal(unsigned bits) {
    // JAX uniform(lo=nextafter(-1,0), hi=1): f in [0,1), u = f*2 + lo
    // (hi-lo rounds to exactly 2.0f; *2 exact so mul+add == fma)
    float f = __uint_as_float((bits >> 9) | 0x3F800000u) - 1.0f;
    const float lo = -0.99999994f;
    float u = __fadd_rn(__fmul_rn(f, 2.0f), lo);
    u = fmaxf(lo, u);
    // XLA ErfInv32 polynomial
    float w = -log1pf(-(u * u));
    float p;
    if (w < 5.0f) {
        w -= 2.5f;
        p = 2.81022636e-08f;
        p = fmaf(p, w, 3.43273939e-07f);
        p = fmaf(p, w, -3.5233877e-06f);
        p = fmaf(p, w, -4.39150654e-06f);
        p = fmaf(p, w, 0.00021858087f);
        p = fmaf(p, w, -0.00125372503f);
        p = fmaf(p, w, -0.00417768164f);
        p = fmaf(p, w, 0.246640727f);
        p = fmaf(p, w, 1.50140941f);
    } else {
        w = sqrtf(w) - 3.0f;
        p = -0.000200214257f;
        p = fmaf(p, w, 0.000100950558f);
        p = fmaf(p, w, 0.00134934322f);
        p = fmaf(p, w, -0.00367342844f);
        p = fmaf(p, w, 0.00573950773f);
        p = fmaf(p, w, -0.0076224613f);
        p = fmaf(p, w, 0.00943887047f);
        p = fmaf(p, w, 1.00167406f);
        p = fmaf(p, w, 2.83297682f);
    }
    return 1.41421356f * (p * u);   // sqrt(2) as f32
}

__global__ __launch_bounds__(TPB) void samples_kernel(
    const float* __restrict__ mean_v, const float* __restrict__ std_v,
    float* __restrict__ samples)
{
    int t = blockIdx.x * TPB + threadIdx.x;
    if (t >= NHID / 4) return;
    float4 m = ((const float4*)mean_v)[t];
    float4 s = ((const float4*)std_v)[t];
    float e[4];
    #pragma unroll
    for (int q = 0; q < 4; q++) {
        unsigned i = 4u * (unsigned)t + (unsigned)q;
        e[q] = bits_to_normal(threefry_xor(0u, i));
    }
    float4 r;
    r.x = fmaf(e[0], s.x, m.x);
    r.y = fmaf(e[1], s.y, m.y);
    r.z = fmaf(e[2], s.z, m.z);
    r.w = fmaf(e[3], s.w, m.w);
    ((float4*)samples)[t] = r;
}

// ---------------------------------------------------------------------------
// Orchestration. d_out regions used as scratch:
//   S = samples region (holds h throughout), M/V = mean/std regions (hold agg,
//   then receive final layernorm outputs).
// ---------------------------------------------------------------------------
extern "C" void kernel_launch(void* const* d_in, const int* in_sizes, int n_in,
                              void* d_out, int out_size, void* d_ws, size_t ws_size,
                              hipStream_t stream)
{
    const float* x     = (const float*)d_in[0];
    const int*   esrc  = (const int*)d_in[1];
    const int*   edst  = (const int*)d_in[2];
    const float* prm[2][7];
    for (int p = 0; p < 2; p++)
        for (int i = 0; i < 7; i++)
            prm[p][i] = (const float*)d_in[3 + p * 7 + i];
    // prm[p]: 0=W1(L,D,D) 1=b1(L,D) 2=W2(L,D,D) 3=b2(L,D) 4=eps(L) 5=Wout 6=bout
    const float* gamma = (const float*)d_in[17];
    const float* beta  = (const float*)d_in[18];

    float* S = (float*)d_out;
    float* M = S + NHID;
    float* V = M + NHID;

    const dim3 gScatter(NEDGES / 8);   // NEDGES*32 threads / 256
    const dim3 gGemm(512);
    const dim3 gSamp((NHID / 4 + TPB - 1) / TPB);

    for (int p = 0; p < 2; p++) {
        const float* W1  = prm[p][0];
        const float* b1  = prm[p][1];
        const float* W2  = prm[p][2];
        const float* b2  = prm[p][3];
        const float* eps = prm[p][4];
        const float* Wo  = prm[p][5];
        const float* bo  = prm[p][6];
        float* AGG = (p == 0) ? M : V;
        float* OUT = (p == 0) ? M : V;

        const float* h = x;
        for (int l = 0; l < 3; l++) {
            hipMemsetAsync(AGG, 0, (size_t)NHID * sizeof(float), stream);
            scatter_add_kernel<<<gScatter, TPB, 0, stream>>>(h, esrc, edst, AGG);
            gemm128_kernel<<<gGemm, TPB, 0, stream>>>(
                h, AGG, eps, l, W1 + (size_t)l * DIM * DIM, b1 + l * DIM,
                nullptr, nullptr, S, 1);
            gemm128_kernel<<<gGemm, TPB, 0, stream>>>(
                S, nullptr, nullptr, 0, W2 + (size_t)l * DIM * DIM, b2 + l * DIM,
                nullptr, nullptr, S, 0);
            h = S;
        }
        gemm128_kernel<<<gGemm, TPB, 0, stream>>>(
            S, nullptr, nullptr, 0, Wo, bo, gamma, beta, OUT, 2);
    }

    samples_kernel<<<gSamp, TPB, 0, stream>>>(M, V, S);
}

// Round 4
// 1556.663 us; speedup vs baseline: 10.7336x; 10.7336x over previous
//
#include <hip/hip_runtime.h>
#include <math.h>

#define NNODES 50000
#define NEDGES 1600000
#define DIM    128
#define NHID   (NNODES * DIM)      // 6,400,000
#define TPB    256
#define ROWS   32

// ===========================================================================
// CSR build (once per launch, in d_ws):
//   off[50001]  : exclusive prefix of per-dst degree
//   cursor[50000]: scatter cursors (trashed by bucket pass)
//   bucket[NEDGES]: src ids grouped by dst
// ===========================================================================
__global__ __launch_bounds__(TPB) void hist_kernel(
    const int* __restrict__ dst, int* __restrict__ deg)
{
    int e = blockIdx.x * TPB + threadIdx.x;
    if (e < NEDGES) atomicAdd(&deg[dst[e]], 1);
}

// Single-block exclusive scan of deg[NNODES] (in place -> offsets), also
// copies offsets to cursor, and writes off[NNODES] = total.
__global__ __launch_bounds__(1024) void scan_kernel(
    int* __restrict__ off, int* __restrict__ cursor)
{
    __shared__ int buf[1024];
    __shared__ int carry;
    const int tid = threadIdx.x;
    if (tid == 0) carry = 0;
    __syncthreads();
    for (int chunk = 0; chunk < NNODES; chunk += 1024) {
        int i = chunk + tid;
        int v = (i < NNODES) ? off[i] : 0;
        buf[tid] = v;
        __syncthreads();
        #pragma unroll
        for (int s = 1; s < 1024; s <<= 1) {
            int t = (tid >= s) ? buf[tid - s] : 0;
            __syncthreads();
            buf[tid] += t;
            __syncthreads();
        }
        int excl = carry + buf[tid] - v;
        if (i < NNODES) { off[i] = excl; cursor[i] = excl; }
        __syncthreads();
        if (tid == 0) carry += buf[1023];
        __syncthreads();
    }
    if (tid == 0) off[NNODES] = carry;   // == NEDGES
}

__global__ __launch_bounds__(TPB) void bucket_kernel(
    const int* __restrict__ src, const int* __restrict__ dst,
    int* __restrict__ cursor, int* __restrict__ bucket)
{
    int e = blockIdx.x * TPB + threadIdx.x;
    if (e >= NEDGES) return;
    int pos = atomicAdd(&cursor[dst[e]], 1);
    bucket[pos] = src[e];
}

// ---------------------------------------------------------------------------
// Gather aggregation: agg[i] = sum_{j in bucket[off[i]:off[i+1]]} h[j]
// One wave per node, float2 per lane (64*2 = 128 cols, 512 B coalesced/edge).
// Zero-degree nodes write zeros (segment_sum semantics); no memset needed.
// ---------------------------------------------------------------------------
__global__ __launch_bounds__(TPB) void gather_agg_kernel(
    const float* __restrict__ h, const int* __restrict__ off,
    const int* __restrict__ bucket, float* __restrict__ agg)
{
    int node = blockIdx.x * (TPB / 64) + (threadIdx.x >> 6);
    int lane = threadIdx.x & 63;
    if (node >= NNODES) return;
    int j0 = off[node], j1 = off[node + 1];
    const float* base = h + 2 * lane;
    float2 acc = make_float2(0.0f, 0.0f);
    int j = j0;
    for (; j + 1 < j1; j += 2) {          // 2-way unroll: 2 loads in flight
        int s0 = bucket[j], s1 = bucket[j + 1];
        float2 v0 = *(const float2*)(base + (size_t)s0 * DIM);
        float2 v1 = *(const float2*)(base + (size_t)s1 * DIM);
        acc.x += v0.x; acc.y += v0.y;
        acc.x += v1.x; acc.y += v1.y;
    }
    if (j < j1) {
        int s0 = bucket[j];
        float2 v0 = *(const float2*)(base + (size_t)s0 * DIM);
        acc.x += v0.x; acc.y += v0.y;
    }
    *(float2*)(agg + (size_t)node * DIM + 2 * lane) = acc;
}

// ---------------------------------------------------------------------------
// Fallback scatter-add (used only if ws_size is too small for CSR).
// ---------------------------------------------------------------------------
__global__ __launch_bounds__(TPB) void scatter_add_kernel(
    const float* __restrict__ h, const int* __restrict__ src,
    const int* __restrict__ dst, float* __restrict__ agg)
{
    long tid = (long)blockIdx.x * TPB + threadIdx.x;
    int e = (int)(tid >> 5);
    int c = (int)(tid & 31);
    if (e >= NEDGES) return;
    int s = src[e], d = dst[e];
    float4 v = ((const float4*)(h + (size_t)s * DIM))[c];
    float* o = agg + (size_t)d * DIM + c * 4;
    atomicAdd(o + 0, v.x);
    atomicAdd(o + 1, v.y);
    atomicAdd(o + 2, v.z);
    atomicAdd(o + 3, v.w);
}

// ---------------------------------------------------------------------------
// 128x128 GEMM over row tiles, fused prologue/epilogue.
//   z = (agg ? scale*hin + agg : hin)            [row tile staged in LDS]
//   y = z @ W + bias
//   mode 0: out = y;  mode 1: out = sigmoid(y);  mode 2: out = layernorm(y)
// In-place (out == hin) safe: rows staged in LDS, blocks own disjoint rows.
// ---------------------------------------------------------------------------
__global__ __launch_bounds__(TPB) void gemm128_kernel(
    const float* hin, const float* __restrict__ agg,
    const float* __restrict__ eps_ptr, int eps_idx,
    const float* __restrict__ W, const float* __restrict__ bias,
    const float* __restrict__ gamma, const float* __restrict__ beta,
    float* out, int mode)
{
    __shared__ float sW[DIM * DIM];   // 64 KB
    __shared__ float sZ[ROWS * DIM];  // 16 KB  -> 80 KB total, 2 blocks/CU

    {   // load weights once per block
        const float4* Wv = (const float4*)W;
        float4* sWv = (float4*)sW;
        #pragma unroll
        for (int i = 0; i < (DIM * DIM / 4) / TPB; i++)
            sWv[threadIdx.x + i * TPB] = Wv[threadIdx.x + i * TPB];
    }

    float scale = 1.0f;
    if (agg != nullptr) scale = 1.0f + eps_ptr[eps_idx];

    const int tx = threadIdx.x & 31;   // column group: cols 4tx..4tx+3
    const int ty = threadIdx.x >> 5;   // row group: rows ty+8j, j<4

    float4 bv = ((const float4*)bias)[tx];
    float4 gv = make_float4(0, 0, 0, 0), btv = make_float4(0, 0, 0, 0);
    if (mode == 2) { gv = ((const float4*)gamma)[tx]; btv = ((const float4*)beta)[tx]; }

    const int ntiles = (NNODES + ROWS - 1) / ROWS;
    for (int tile = blockIdx.x; tile < ntiles; tile += gridDim.x) {
        const int r0 = tile * ROWS;
        const int nrows = min(ROWS, NNODES - r0);
        __syncthreads();  // protect sZ reuse (and first-iter W load)
        {
            const float4* hv = (const float4*)(hin + (size_t)r0 * DIM);
            float4* sZv = (float4*)sZ;
            const int cnt = nrows * (DIM / 4);
            if (agg != nullptr) {
                const float4* av = (const float4*)(agg + (size_t)r0 * DIM);
                for (int i = threadIdx.x; i < cnt; i += TPB) {
                    float4 hx = hv[i], ax = av[i], z;
                    z.x = fmaf(scale, hx.x, ax.x);
                    z.y = fmaf(scale, hx.y, ax.y);
                    z.z = fmaf(scale, hx.z, ax.z);
                    z.w = fmaf(scale, hx.w, ax.w);
                    sZv[i] = z;
                }
            } else {
                for (int i = threadIdx.x; i < cnt; i += TPB) sZv[i] = hv[i];
            }
        }
        __syncthreads();

        float4 acc[4];
        #pragma unroll
        for (int j = 0; j < 4; j++) acc[j] = make_float4(0, 0, 0, 0);

        const float4* sWv = (const float4*)sW;
        #pragma unroll 4
        for (int k = 0; k < DIM; k++) {
            float4 w4 = sWv[k * (DIM / 4) + tx];
            #pragma unroll
            for (int j = 0; j < 4; j++) {
                float zk = sZ[(ty + 8 * j) * DIM + k];
                acc[j].x = fmaf(zk, w4.x, acc[j].x);
                acc[j].y = fmaf(zk, w4.y, acc[j].y);
                acc[j].z = fmaf(zk, w4.z, acc[j].z);
                acc[j].w = fmaf(zk, w4.w, acc[j].w);
            }
        }

        #pragma unroll
        for (int j = 0; j < 4; j++) {
            int rl = ty + 8 * j;
            float4 v = acc[j];
            v.x += bv.x; v.y += bv.y; v.z += bv.z; v.w += bv.w;
            if (mode == 1) {
                v.x = 1.0f / (1.0f + expf(-v.x));
                v.y = 1.0f / (1.0f + expf(-v.y));
                v.z = 1.0f / (1.0f + expf(-v.z));
                v.w = 1.0f / (1.0f + expf(-v.w));
            } else if (mode == 2) {
                float s1 = v.x + v.y + v.z + v.w;
                float s2 = fmaf(v.x, v.x, fmaf(v.y, v.y, fmaf(v.z, v.z, v.w * v.w)));
                #pragma unroll
                for (int m = 16; m >= 1; m >>= 1) {   // xor<32 stays in tx-half
                    s1 += __shfl_xor(s1, m);
                    s2 += __shfl_xor(s2, m);
                }
                float mean = s1 * (1.0f / DIM);
                float var  = s2 * (1.0f / DIM) - mean * mean;
                float rstd = rsqrtf(var + 1e-5f);
                v.x = fmaf((v.x - mean) * rstd, gv.x, btv.x);
                v.y = fmaf((v.y - mean) * rstd, gv.y, btv.y);
                v.z = fmaf((v.z - mean) * rstd, gv.z, btv.z);
                v.w = fmaf((v.w - mean) * rstd, gv.w, btv.w);
            }
            if (rl < nrows)
                ((float4*)(out + (size_t)(r0 + rl) * DIM))[tx] = v;
        }
    }
}

// ---------------------------------------------------------------------------
// samples = mean_v + eps * std_v with eps = jax.random.normal(key(42)) under
// jax_threefry_partitionable=True: per flat element i, block inputs
// (hi=0, lo=i), bits = out0 ^ out1, key=(0,42).
// ---------------------------------------------------------------------------
__device__ __forceinline__ unsigned rotl32(unsigned x, int r) {
    return (x << r) | (x >> (32 - r));
}

__device__ __forceinline__ unsigned threefry_xor(unsigned c0, unsigned c1) {
    const unsigned k0 = 0u, k1 = 42u;
    const unsigned k2 = k0 ^ k1 ^ 0x1BD11BDAu;
    unsigned x0 = c0 + k0;
    unsigned x1 = c1 + k1;
#define TF_ROUND(R) { x0 += x1; x1 = rotl32(x1, R); x1 ^= x0; }
    TF_ROUND(13) TF_ROUND(15) TF_ROUND(26) TF_ROUND(6)
    x0 += k1; x1 += k2 + 1u;
    TF_ROUND(17) TF_ROUND(29) TF_ROUND(16) TF_ROUND(24)
    x0 += k2; x1 += k0 + 2u;
    TF_ROUND(13) TF_ROUND(15) TF_ROUND(26) TF_ROUND(6)
    x0 += k0; x1 += k1 + 3u;
    TF_ROUND(17) TF_ROUND(29) TF_ROUND(16) TF_ROUND(24)
    x0 += k1; x1 += k2 + 4u;
    TF_ROUND(13) TF_ROUND(15) TF_ROUND(26) TF_ROUND(6)
    x0 += k2; x1 += k0 + 5u;
#undef TF_ROUND
    return x0 ^ x1;
}

__device__ __forceinline__ float bits_to_normal(unsigned bits) {
    float f = __uint_as_float((bits >> 9) | 0x3F800000u) - 1.0f;
    const float lo = -0.99999994f;
    float u = __fadd_rn(__fmul_rn(f, 2.0f), lo);
    u = fmaxf(lo, u);
    float w = -log1pf(-(u * u));
    float p;
    if (w < 5.0f) {
        w -= 2.5f;
        p = 2.81022636e-08f;
        p = fmaf(p, w, 3.43273939e-07f);
        p = fmaf(p, w, -3.5233877e-06f);
        p = fmaf(p, w, -4.39150654e-06f);
        p = fmaf(p, w, 0.00021858087f);
        p = fmaf(p, w, -0.00125372503f);
        p = fmaf(p, w, -0.00417768164f);
        p = fmaf(p, w, 0.246640727f);
        p = fmaf(p, w, 1.50140941f);
    } else {
        w = sqrtf(w) - 3.0f;
        p = -0.000200214257f;
        p = fmaf(p, w, 0.000100950558f);
        p = fmaf(p, w, 0.00134934322f);
        p = fmaf(p, w, -0.00367342844f);
        p = fmaf(p, w, 0.00573950773f);
        p = fmaf(p, w, -0.0076224613f);
        p = fmaf(p, w, 0.00943887047f);
        p = fmaf(p, w, 1.00167406f);
        p = fmaf(p, w, 2.83297682f);
    }
    return 1.41421356f * (p * u);
}

__global__ __launch_bounds__(TPB) void samples_kernel(
    const float* __restrict__ mean_v, const float* __restrict__ std_v,
    float* __restrict__ samples)
{
    int t = blockIdx.x * TPB + threadIdx.x;
    if (t >= NHID / 4) return;
    float4 m = ((const float4*)mean_v)[t];
    float4 s = ((const float4*)std_v)[t];
    float e[4];
    #pragma unroll
    for (int q = 0; q < 4; q++) {
        unsigned i = 4u * (unsigned)t + (unsigned)q;
        e[q] = bits_to_normal(threefry_xor(0u, i));
    }
    float4 r;
    r.x = fmaf(e[0], s.x, m.x);
    r.y = fmaf(e[1], s.y, m.y);
    r.z = fmaf(e[2], s.z, m.z);
    r.w = fmaf(e[3], s.w, m.w);
    ((float4*)samples)[t] = r;
}

// ---------------------------------------------------------------------------
// Orchestration. d_out regions: S (holds h), M/V (agg then final outputs).
// d_ws: CSR (off 50001 + cursor 50000 + bucket NEDGES ints = ~6.8 MB).
// ---------------------------------------------------------------------------
extern "C" void kernel_launch(void* const* d_in, const int* in_sizes, int n_in,
                              void* d_out, int out_size, void* d_ws, size_t ws_size,
                              hipStream_t stream)
{
    const float* x     = (const float*)d_in[0];
    const int*   esrc  = (const int*)d_in[1];
    const int*   edst  = (const int*)d_in[2];
    const float* prm[2][7];
    for (int p = 0; p < 2; p++)
        for (int i = 0; i < 7; i++)
            prm[p][i] = (const float*)d_in[3 + p * 7 + i];
    const float* gamma = (const float*)d_in[17];
    const float* beta  = (const float*)d_in[18];

    float* S = (float*)d_out;
    float* M = S + NHID;
    float* V = M + NHID;

    const size_t csr_bytes = (size_t)(NNODES + 1 + NNODES + NEDGES) * sizeof(int);
    const bool use_csr = (ws_size >= csr_bytes);
    int* off    = (int*)d_ws;
    int* cursor = off + (NNODES + 1);
    int* bucket = cursor + NNODES;

    const dim3 gEdge((NEDGES + TPB - 1) / TPB);
    const dim3 gGather((NNODES + (TPB / 64) - 1) / (TPB / 64));
    const dim3 gScatter(NEDGES / 8);
    const dim3 gGemm(512);
    const dim3 gSamp((NHID / 4 + TPB - 1) / TPB);

    if (use_csr) {   // build CSR once; reused by all 6 aggregation passes
        hipMemsetAsync(off, 0, (size_t)NNODES * sizeof(int), stream);
        hist_kernel<<<gEdge, TPB, 0, stream>>>(edst, off);
        scan_kernel<<<1, 1024, 0, stream>>>(off, cursor);
        bucket_kernel<<<gEdge, TPB, 0, stream>>>(esrc, edst, cursor, bucket);
    }

    for (int p = 0; p < 2; p++) {
        const float* W1  = prm[p][0];
        const float* b1  = prm[p][1];
        const float* W2  = prm[p][2];
        const float* b2  = prm[p][3];
        const float* eps = prm[p][4];
        const float* Wo  = prm[p][5];
        const float* bo  = prm[p][6];
        float* AGG = (p == 0) ? M : V;
        float* OUT = (p == 0) ? M : V;

        const float* h = x;
        for (int l = 0; l < 3; l++) {
            if (use_csr) {
                gather_agg_kernel<<<gGather, TPB, 0, stream>>>(h, off, bucket, AGG);
            } else {
                hipMemsetAsync(AGG, 0, (size_t)NHID * sizeof(float), stream);
                scatter_add_kernel<<<gScatter, TPB, 0, stream>>>(h, esrc, edst, AGG);
            }
            gemm128_kernel<<<gGemm, TPB, 0, stream>>>(
                h, AGG, eps, l, W1 + (size_t)l * DIM * DIM, b1 + l * DIM,
                nullptr, nullptr, S, 1);
            gemm128_kernel<<<gGemm, TPB, 0, stream>>>(
                S, nullptr, nullptr, 0, W2 + (size_t)l * DIM * DIM, b2 + l * DIM,
                nullptr, nullptr, S, 0);
            h = S;
        }
        gemm128_kernel<<<gGemm, TPB, 0, stream>>>(
            S, nullptr, nullptr, 0, Wo, bo, gamma, beta, OUT, 2);
    }

    samples_kernel<<<gSamp, TPB, 0, stream>>>(M, V, S);
}

// Round 5
// 1315.855 us; speedup vs baseline: 12.6979x; 1.1830x over previous
//
#include <hip/hip_runtime.h>
#include <math.h>

#define NNODES 50000
#define NEDGES 1600000
#define DIM    128
#define NHID   (NNODES * DIM)      // 6,400,000
#define TPB    256
#define ROWS   32

typedef unsigned short bf16_t;

__device__ __forceinline__ float bf_lo(unsigned u) { return __uint_as_float(u << 16); }
__device__ __forceinline__ float bf_hi(unsigned u) { return __uint_as_float(u & 0xFFFF0000u); }
__device__ __forceinline__ bf16_t f2bf(float f) {   // RNE
    unsigned u = __float_as_uint(f);
    u += 0x7FFFu + ((u >> 16) & 1u);
    return (bf16_t)(u >> 16);
}

// ===========================================================================
// CSR build (once per launch, in d_ws):
//   off[50001], cursor[50000], bucket[NEDGES]  (~6.8 MB)
// ===========================================================================
__global__ __launch_bounds__(TPB) void hist_kernel(
    const int* __restrict__ dst, int* __restrict__ deg)
{
    int e = blockIdx.x * TPB + threadIdx.x;
    if (e < NEDGES) atomicAdd(&deg[dst[e]], 1);
}

// Single-block exclusive scan (wave-shuffle + cross-wave LDS, 3 barriers/chunk)
__global__ __launch_bounds__(1024) void scan_kernel(
    int* __restrict__ off, int* __restrict__ cursor)
{
    __shared__ int wsum[16];
    __shared__ int carry_s;
    const int tid = threadIdx.x, wid = tid >> 6, lane = tid & 63;
    if (tid == 0) carry_s = 0;
    __syncthreads();
    for (int chunk = 0; chunk < NNODES; chunk += 1024) {
        int i = chunk + tid;
        int v = (i < NNODES) ? off[i] : 0;
        int s = v;                         // inclusive wave scan
        #pragma unroll
        for (int d = 1; d < 64; d <<= 1) {
            int t = __shfl_up(s, d);
            if (lane >= d) s += t;
        }
        if (lane == 63) wsum[wid] = s;
        __syncthreads();
        if (wid == 0) {                    // scan the 16 wave sums (all lanes active)
            int ws = (lane < 16) ? wsum[lane] : 0;
            #pragma unroll
            for (int d = 1; d < 16; d <<= 1) {
                int t = __shfl_up(ws, d);
                if (lane >= d) ws += t;
            }
            if (lane < 16) wsum[lane] = ws;
        }
        __syncthreads();
        int carry = carry_s;
        int wprefix = (wid == 0) ? 0 : wsum[wid - 1];
        int excl = carry + wprefix + s - v;
        if (i < NNODES) { off[i] = excl; cursor[i] = excl; }
        __syncthreads();
        if (tid == 0) carry_s = carry + wsum[15];
    }
    __syncthreads();
    if (tid == 0) off[NNODES] = carry_s;   // == NEDGES
}

__global__ __launch_bounds__(TPB) void bucket_kernel(
    const int* __restrict__ src, const int* __restrict__ dst,
    int* __restrict__ cursor, int* __restrict__ bucket)
{
    int e = blockIdx.x * TPB + threadIdx.x;
    if (e >= NEDGES) return;
    int pos = atomicAdd(&cursor[dst[e]], 1);
    bucket[pos] = src[e];
}

// ---------------------------------------------------------------------------
// Gather aggregation (fp32 h): agg[i] = sum over bucket rows. Wave per node.
// ---------------------------------------------------------------------------
__global__ __launch_bounds__(TPB) void gather_agg_f32_kernel(
    const float* __restrict__ h, const int* __restrict__ off,
    const int* __restrict__ bucket, float* __restrict__ agg)
{
    int node = blockIdx.x * (TPB / 64) + (threadIdx.x >> 6);
    int lane = threadIdx.x & 63;
    if (node >= NNODES) return;
    int j0 = off[node], j1 = off[node + 1];
    const float* base = h + 2 * lane;
    float ax = 0.0f, ay = 0.0f;
    int j = j0;
    for (; j + 1 < j1; j += 2) {
        int s0 = bucket[j], s1 = bucket[j + 1];
        float2 v0 = *(const float2*)(base + (size_t)s0 * DIM);
        float2 v1 = *(const float2*)(base + (size_t)s1 * DIM);
        ax += v0.x; ay += v0.y;
        ax += v1.x; ay += v1.y;
    }
    if (j < j1) {
        float2 v0 = *(const float2*)(base + (size_t)bucket[j] * DIM);
        ax += v0.x; ay += v0.y;
    }
    *(float2*)(agg + (size_t)node * DIM + 2 * lane) = make_float2(ax, ay);
}

// bf16-h variant: one uint (2 bf16) per lane per row, 256 B/row coalesced.
__global__ __launch_bounds__(TPB) void gather_agg_bf16_kernel(
    const bf16_t* __restrict__ hb, const int* __restrict__ off,
    const int* __restrict__ bucket, float* __restrict__ agg)
{
    int node = blockIdx.x * (TPB / 64) + (threadIdx.x >> 6);
    int lane = threadIdx.x & 63;
    if (node >= NNODES) return;
    int j0 = off[node], j1 = off[node + 1];
    const unsigned* base = (const unsigned*)hb + lane;
    float ax = 0.0f, ay = 0.0f;
    int j = j0;
    for (; j + 1 < j1; j += 2) {
        int s0 = bucket[j], s1 = bucket[j + 1];
        unsigned u0 = base[(size_t)s0 * (DIM / 2)];
        unsigned u1 = base[(size_t)s1 * (DIM / 2)];
        ax += bf_lo(u0); ay += bf_hi(u0);
        ax += bf_lo(u1); ay += bf_hi(u1);
    }
    if (j < j1) {
        unsigned u0 = base[(size_t)bucket[j] * (DIM / 2)];
        ax += bf_lo(u0); ay += bf_hi(u0);
    }
    *(float2*)(agg + (size_t)node * DIM + 2 * lane) = make_float2(ax, ay);
}

// ---------------------------------------------------------------------------
// 128x128 GEMM over 32-row tiles, fused prologue/epilogue, templated dtypes.
//   z = (HAS_AGG ? scale*hin + agg : hin)   staged fp32 in LDS
//   y = z @ W + bias
//   MODE 0: y;  MODE 1: sigmoid(y);  MODE 2: layernorm(y)*gamma+beta
// In-place safe: rows staged to LDS before writeback, disjoint row ownership.
// ---------------------------------------------------------------------------
template <class HinT, class HoutT, int MODE, bool HAS_AGG>
__global__ __launch_bounds__(TPB) void gemm128_kernel(
    const HinT* hin, const float* __restrict__ agg,
    const float* __restrict__ eps_ptr, int eps_idx,
    const float* __restrict__ W, const float* __restrict__ bias,
    const float* __restrict__ gamma, const float* __restrict__ beta,
    HoutT* out)
{
    __shared__ float sW[DIM * DIM];   // 64 KB
    __shared__ float sZ[ROWS * DIM];  // 16 KB  -> 80 KB, 2 blocks/CU

    {
        const float4* Wv = (const float4*)W;
        float4* sWv = (float4*)sW;
        #pragma unroll
        for (int i = 0; i < (DIM * DIM / 4) / TPB; i++)
            sWv[threadIdx.x + i * TPB] = Wv[threadIdx.x + i * TPB];
    }

    float scale = 1.0f;
    if (HAS_AGG) scale = 1.0f + eps_ptr[eps_idx];

    const int tx = threadIdx.x & 31;   // cols 4tx..4tx+3
    const int ty = threadIdx.x >> 5;   // rows ty+8j

    float4 bv = ((const float4*)bias)[tx];
    float4 gv = make_float4(0, 0, 0, 0), btv = make_float4(0, 0, 0, 0);
    if (MODE == 2) { gv = ((const float4*)gamma)[tx]; btv = ((const float4*)beta)[tx]; }

    const int ntiles = (NNODES + ROWS - 1) / ROWS;
    for (int tile = blockIdx.x; tile < ntiles; tile += gridDim.x) {
        const int r0 = tile * ROWS;
        const int nrows = min(ROWS, NNODES - r0);
        __syncthreads();
        {   // stage z tile (fp32) into sZ
            float4* sZv = (float4*)sZ;
            const float4* av = HAS_AGG ? (const float4*)(agg + (size_t)r0 * DIM) : nullptr;
            if constexpr (sizeof(HinT) == 4) {   // fp32 input
                const float4* hv = (const float4*)(hin + (size_t)r0 * DIM);
                const int cnt = nrows * (DIM / 4);
                for (int i = threadIdx.x; i < cnt; i += TPB) {
                    float4 hx = hv[i];
                    if (HAS_AGG) {
                        float4 ax = av[i];
                        hx.x = fmaf(scale, hx.x, ax.x);
                        hx.y = fmaf(scale, hx.y, ax.y);
                        hx.z = fmaf(scale, hx.z, ax.z);
                        hx.w = fmaf(scale, hx.w, ax.w);
                    }
                    sZv[i] = hx;
                }
            } else {                             // bf16 input: uint4 = 8 els
                const uint4* hv = (const uint4*)(hin + (size_t)r0 * DIM);
                const int cnt = nrows * (DIM / 8);
                for (int i = threadIdx.x; i < cnt; i += TPB) {
                    uint4 hx = hv[i];
                    float4 z0, z1;
                    z0.x = bf_lo(hx.x); z0.y = bf_hi(hx.x);
                    z0.z = bf_lo(hx.y); z0.w = bf_hi(hx.y);
                    z1.x = bf_lo(hx.z); z1.y = bf_hi(hx.z);
                    z1.z = bf_lo(hx.w); z1.w = bf_hi(hx.w);
                    if (HAS_AGG) {
                        float4 a0 = av[2 * i], a1 = av[2 * i + 1];
                        z0.x = fmaf(scale, z0.x, a0.x);
                        z0.y = fmaf(scale, z0.y, a0.y);
                        z0.z = fmaf(scale, z0.z, a0.z);
                        z0.w = fmaf(scale, z0.w, a0.w);
                        z1.x = fmaf(scale, z1.x, a1.x);
                        z1.y = fmaf(scale, z1.y, a1.y);
                        z1.z = fmaf(scale, z1.z, a1.z);
                        z1.w = fmaf(scale, z1.w, a1.w);
                    }
                    sZv[2 * i]     = z0;
                    sZv[2 * i + 1] = z1;
                }
            }
        }
        __syncthreads();

        float4 acc[4];
        #pragma unroll
        for (int j = 0; j < 4; j++) acc[j] = make_float4(0, 0, 0, 0);

        const float4* sWv = (const float4*)sW;
        #pragma unroll 4
        for (int k = 0; k < DIM; k++) {
            float4 w4 = sWv[k * (DIM / 4) + tx];
            #pragma unroll
            for (int j = 0; j < 4; j++) {
                float zk = sZ[(ty + 8 * j) * DIM + k];
                acc[j].x = fmaf(zk, w4.x, acc[j].x);
                acc[j].y = fmaf(zk, w4.y, acc[j].y);
                acc[j].z = fmaf(zk, w4.z, acc[j].z);
                acc[j].w = fmaf(zk, w4.w, acc[j].w);
            }
        }

        #pragma unroll
        for (int j = 0; j < 4; j++) {
            int rl = ty + 8 * j;
            float4 v = acc[j];
            v.x += bv.x; v.y += bv.y; v.z += bv.z; v.w += bv.w;
            if (MODE == 1) {
                v.x = 1.0f / (1.0f + expf(-v.x));
                v.y = 1.0f / (1.0f + expf(-v.y));
                v.z = 1.0f / (1.0f + expf(-v.z));
                v.w = 1.0f / (1.0f + expf(-v.w));
            } else if (MODE == 2) {
                float s1 = v.x + v.y + v.z + v.w;
                float s2 = fmaf(v.x, v.x, fmaf(v.y, v.y, fmaf(v.z, v.z, v.w * v.w)));
                #pragma unroll
                for (int m = 16; m >= 1; m >>= 1) {
                    s1 += __shfl_xor(s1, m);
                    s2 += __shfl_xor(s2, m);
                }
                float mean = s1 * (1.0f / DIM);
                float var  = s2 * (1.0f / DIM) - mean * mean;
                float rstd = rsqrtf(var + 1e-5f);
                v.x = fmaf((v.x - mean) * rstd, gv.x, btv.x);
                v.y = fmaf((v.y - mean) * rstd, gv.y, btv.y);
                v.z = fmaf((v.z - mean) * rstd, gv.z, btv.z);
                v.w = fmaf((v.w - mean) * rstd, gv.w, btv.w);
            }
            if (rl < nrows) {
                if constexpr (sizeof(HoutT) == 4) {
                    ((float4*)((float*)out + (size_t)(r0 + rl) * DIM))[tx] = v;
                } else {
                    ushort4 o;
                    o.x = f2bf(v.x); o.y = f2bf(v.y);
                    o.z = f2bf(v.z); o.w = f2bf(v.w);
                    ((ushort4*)((bf16_t*)out + (size_t)(r0 + rl) * DIM))[tx] = o;
                }
            }
        }
    }
}

// ---------------------------------------------------------------------------
// samples = mean + eps*std, eps = jax.random.normal(key(42)), partitionable
// threefry: per element i block inputs (0, i), bits = out0 ^ out1, key (0,42).
// ---------------------------------------------------------------------------
__device__ __forceinline__ unsigned rotl32(unsigned x, int r) {
    return (x << r) | (x >> (32 - r));
}

__device__ __forceinline__ unsigned threefry_xor(unsigned c0, unsigned c1) {
    const unsigned k0 = 0u, k1 = 42u;
    const unsigned k2 = k0 ^ k1 ^ 0x1BD11BDAu;
    unsigned x0 = c0 + k0;
    unsigned x1 = c1 + k1;
#define TF_ROUND(R) { x0 += x1; x1 = rotl32(x1, R); x1 ^= x0; }
    TF_ROUND(13) TF_ROUND(15) TF_ROUND(26) TF_ROUND(6)
    x0 += k1; x1 += k2 + 1u;
    TF_ROUND(17) TF_ROUND(29) TF_ROUND(16) TF_ROUND(24)
    x0 += k2; x1 += k0 + 2u;
    TF_ROUND(13) TF_ROUND(15) TF_ROUND(26) TF_ROUND(6)
    x0 += k0; x1 += k1 + 3u;
    TF_ROUND(17) TF_ROUND(29) TF_ROUND(16) TF_ROUND(24)
    x0 += k1; x1 += k2 + 4u;
    TF_ROUND(13) TF_ROUND(15) TF_ROUND(26) TF_ROUND(6)
    x0 += k2; x1 += k0 + 5u;
#undef TF_ROUND
    return x0 ^ x1;
}

__device__ __forceinline__ float bits_to_normal(unsigned bits) {
    float f = __uint_as_float((bits >> 9) | 0x3F800000u) - 1.0f;
    const float lo = -0.99999994f;
    float u = __fadd_rn(__fmul_rn(f, 2.0f), lo);
    u = fmaxf(lo, u);
    float w = -log1pf(-(u * u));
    float p;
    if (w < 5.0f) {
        w -= 2.5f;
        p = 2.81022636e-08f;
        p = fmaf(p, w, 3.43273939e-07f);
        p = fmaf(p, w, -3.5233877e-06f);
        p = fmaf(p, w, -4.39150654e-06f);
        p = fmaf(p, w, 0.00021858087f);
        p = fmaf(p, w, -0.00125372503f);
        p = fmaf(p, w, -0.00417768164f);
        p = fmaf(p, w, 0.246640727f);
        p = fmaf(p, w, 1.50140941f);
    } else {
        w = sqrtf(w) - 3.0f;
        p = -0.000200214257f;
        p = fmaf(p, w, 0.000100950558f);
        p = fmaf(p, w, 0.00134934322f);
        p = fmaf(p, w, -0.00367342844f);
        p = fmaf(p, w, 0.00573950773f);
        p = fmaf(p, w, -0.0076224613f);
        p = fmaf(p, w, 0.00943887047f);
        p = fmaf(p, w, 1.00167406f);
        p = fmaf(p, w, 2.83297682f);
    }
    return 1.41421356f * (p * u);
}

__global__ __launch_bounds__(TPB) void samples_kernel(
    const float* __restrict__ mean_v, const float* __restrict__ std_v,
    float* __restrict__ samples)
{
    int t = blockIdx.x * TPB + threadIdx.x;
    if (t >= NHID / 4) return;
    float4 m = ((const float4*)mean_v)[t];
    float4 s = ((const float4*)std_v)[t];
    float e[4];
    #pragma unroll
    for (int q = 0; q < 4; q++) {
        unsigned i = 4u * (unsigned)t + (unsigned)q;
        e[q] = bits_to_normal(threefry_xor(0u, i));
    }
    float4 r;
    r.x = fmaf(e[0], s.x, m.x);
    r.y = fmaf(e[1], s.y, m.y);
    r.z = fmaf(e[2], s.z, m.z);
    r.w = fmaf(e[3], s.w, m.w);
    ((float4*)samples)[t] = r;
}

// ---------------------------------------------------------------------------
// Orchestration.
//   S region (d_out[0:NHID] fp32): holds bf16 h (first 12.8 MB) during GIN,
//     then fp32 samples at the end.
//   M: p0 aggs (l1,l2) then mean_v.  V: SHARED l0 agg (both paths), then p1
//     aggs, then std_v.  p1's l0 gemm reads V before p1's l1 gather clobbers.
//   d_ws: CSR (off + cursor + bucket, ~6.8 MB).
// ---------------------------------------------------------------------------
extern "C" void kernel_launch(void* const* d_in, const int* in_sizes, int n_in,
                              void* d_out, int out_size, void* d_ws, size_t ws_size,
                              hipStream_t stream)
{
    const float* x     = (const float*)d_in[0];
    const int*   esrc  = (const int*)d_in[1];
    const int*   edst  = (const int*)d_in[2];
    const float* prm[2][7];
    for (int p = 0; p < 2; p++)
        for (int i = 0; i < 7; i++)
            prm[p][i] = (const float*)d_in[3 + p * 7 + i];
    const float* gamma = (const float*)d_in[17];
    const float* beta  = (const float*)d_in[18];

    float*  S  = (float*)d_out;
    bf16_t* Sb = (bf16_t*)d_out;          // bf16 view of S region
    float*  M  = S + NHID;
    float*  V  = M + NHID;

    int* off    = (int*)d_ws;
    int* cursor = off + (NNODES + 1);
    int* bucket = cursor + NNODES;

    const dim3 gEdge((NEDGES + TPB - 1) / TPB);
    const dim3 gGather((NNODES + (TPB / 64) - 1) / (TPB / 64));
    const dim3 gGemm(512);
    const dim3 gSamp((NHID / 4 + TPB - 1) / TPB);

    // CSR build (reused by all aggregation passes)
    hipMemsetAsync(off, 0, (size_t)NNODES * sizeof(int), stream);
    hist_kernel<<<gEdge, TPB, 0, stream>>>(edst, off);
    scan_kernel<<<1, 1024, 0, stream>>>(off, cursor);
    bucket_kernel<<<gEdge, TPB, 0, stream>>>(esrc, edst, cursor, bucket);

    // Shared layer-0 aggregation (path-independent): agg0 = segsum(x[src])
    gather_agg_f32_kernel<<<gGather, TPB, 0, stream>>>(x, off, bucket, V);

    for (int p = 0; p < 2; p++) {
        const float* W1  = prm[p][0];
        const float* b1  = prm[p][1];
        const float* W2  = prm[p][2];
        const float* b2  = prm[p][3];
        const float* eps = prm[p][4];
        const float* Wo  = prm[p][5];
        const float* bo  = prm[p][6];
        float* AGG = (p == 0) ? M : V;
        float* OUT = (p == 0) ? M : V;

        // layer 0: fp32 x + shared agg (V)
        gemm128_kernel<float, bf16_t, 1, true><<<gGemm, TPB, 0, stream>>>(
            x, V, eps, 0, W1, b1, nullptr, nullptr, Sb);
        gemm128_kernel<bf16_t, bf16_t, 0, false><<<gGemm, TPB, 0, stream>>>(
            Sb, nullptr, nullptr, 0, W2, b2, nullptr, nullptr, Sb);

        // layers 1,2: bf16 h
        for (int l = 1; l < 3; l++) {
            gather_agg_bf16_kernel<<<gGather, TPB, 0, stream>>>(Sb, off, bucket, AGG);
            gemm128_kernel<bf16_t, bf16_t, 1, true><<<gGemm, TPB, 0, stream>>>(
                Sb, AGG, eps, l, W1 + (size_t)l * DIM * DIM, b1 + l * DIM,
                nullptr, nullptr, Sb);
            gemm128_kernel<bf16_t, bf16_t, 0, false><<<gGemm, TPB, 0, stream>>>(
                Sb, nullptr, nullptr, 0, W2 + (size_t)l * DIM * DIM, b2 + l * DIM,
                nullptr, nullptr, Sb);
        }

        // output projection + layernorm -> fp32
        gemm128_kernel<bf16_t, float, 2, false><<<gGemm, TPB, 0, stream>>>(
            Sb, nullptr, nullptr, 0, Wo, bo, gamma, beta, OUT);
    }

    samples_kernel<<<gSamp, TPB, 0, stream>>>(M, V, S);
}

// Round 6
// 1047.968 us; speedup vs baseline: 15.9438x; 1.2556x over previous
//
#include <hip/hip_runtime.h>
#include <math.h>

#define NNODES 50000
#define NEDGES 1600000
#define DIM    128
#define NHID   (NNODES * DIM)      // 6,400,000
#define TPB    256
#define NTILES ((NNODES + 63) / 64)   // 782, 64 rows per block-tile

typedef unsigned short bf16_t;
typedef __attribute__((ext_vector_type(8))) short short8;   // 8 bf16, 4 VGPRs
typedef __attribute__((ext_vector_type(4))) float f32x4;    // MFMA acc

__device__ __forceinline__ float bf_lo(unsigned u) { return __uint_as_float(u << 16); }
__device__ __forceinline__ float bf_hi(unsigned u) { return __uint_as_float(u & 0xFFFF0000u); }
__device__ __forceinline__ bf16_t f2bf(float f) {   // RNE
    unsigned u = __float_as_uint(f);
    u += 0x7FFFu + ((u >> 16) & 1u);
    return (bf16_t)(u >> 16);
}
__device__ __forceinline__ unsigned pack2bf(float a, float b) {
    return (unsigned)f2bf(a) | ((unsigned)f2bf(b) << 16);
}

union S8U { short8 v; uint4 u4; unsigned us[4]; };

// ===========================================================================
// CSR build (once per launch, in d_ws): off[50001], cursor[50000], bucket[NE]
// ===========================================================================
__global__ __launch_bounds__(TPB) void hist_kernel(
    const int* __restrict__ dst, int* __restrict__ deg)
{
    int e = blockIdx.x * TPB + threadIdx.x;
    if (e < NEDGES) atomicAdd(&deg[dst[e]], 1);
}

__global__ __launch_bounds__(1024) void scan_kernel(
    int* __restrict__ off, int* __restrict__ cursor)
{
    __shared__ int wsum[16];
    __shared__ int carry_s;
    const int tid = threadIdx.x, wid = tid >> 6, lane = tid & 63;
    if (tid == 0) carry_s = 0;
    __syncthreads();
    for (int chunk = 0; chunk < NNODES; chunk += 1024) {
        int i = chunk + tid;
        int v = (i < NNODES) ? off[i] : 0;
        int s = v;
        #pragma unroll
        for (int d = 1; d < 64; d <<= 1) {
            int t = __shfl_up(s, d);
            if (lane >= d) s += t;
        }
        if (lane == 63) wsum[wid] = s;
        __syncthreads();
        if (wid == 0) {
            int ws = (lane < 16) ? wsum[lane] : 0;
            #pragma unroll
            for (int d = 1; d < 16; d <<= 1) {
                int t = __shfl_up(ws, d);
                if (lane >= d) ws += t;
            }
            if (lane < 16) wsum[lane] = ws;
        }
        __syncthreads();
        int carry = carry_s;
        int wprefix = (wid == 0) ? 0 : wsum[wid - 1];
        int excl = carry + wprefix + s - v;
        if (i < NNODES) { off[i] = excl; cursor[i] = excl; }
        __syncthreads();
        if (tid == 0) carry_s = carry + wsum[15];
    }
    __syncthreads();
    if (tid == 0) off[NNODES] = carry_s;
}

__global__ __launch_bounds__(TPB) void bucket_kernel(
    const int* __restrict__ src, const int* __restrict__ dst,
    int* __restrict__ cursor, int* __restrict__ bucket)
{
    int e = blockIdx.x * TPB + threadIdx.x;
    if (e >= NEDGES) return;
    int pos = atomicAdd(&cursor[dst[e]], 1);
    bucket[pos] = src[e];
}

// ---------------------------------------------------------------------------
// Gather aggregation, wave per node.
// ---------------------------------------------------------------------------
__global__ __launch_bounds__(TPB) void gather_agg_f32_kernel(
    const float* __restrict__ h, const int* __restrict__ off,
    const int* __restrict__ bucket, float* __restrict__ agg)
{
    int node = blockIdx.x * (TPB / 64) + (threadIdx.x >> 6);
    int lane = threadIdx.x & 63;
    if (node >= NNODES) return;
    int j0 = off[node], j1 = off[node + 1];
    const float* base = h + 2 * lane;
    float ax = 0.0f, ay = 0.0f;
    int j = j0;
    for (; j + 1 < j1; j += 2) {
        int s0 = bucket[j], s1 = bucket[j + 1];
        float2 v0 = *(const float2*)(base + (size_t)s0 * DIM);
        float2 v1 = *(const float2*)(base + (size_t)s1 * DIM);
        ax += v0.x; ay += v0.y;
        ax += v1.x; ay += v1.y;
    }
    if (j < j1) {
        float2 v0 = *(const float2*)(base + (size_t)bucket[j] * DIM);
        ax += v0.x; ay += v0.y;
    }
    *(float2*)(agg + (size_t)node * DIM + 2 * lane) = make_float2(ax, ay);
}

__global__ __launch_bounds__(TPB) void gather_agg_bf16_kernel(
    const bf16_t* __restrict__ hb, const int* __restrict__ off,
    const int* __restrict__ bucket, float* __restrict__ agg)
{
    int node = blockIdx.x * (TPB / 64) + (threadIdx.x >> 6);
    int lane = threadIdx.x & 63;
    if (node >= NNODES) return;
    int j0 = off[node], j1 = off[node + 1];
    const unsigned* base = (const unsigned*)hb + lane;
    float ax = 0.0f, ay = 0.0f;
    int j = j0;
    for (; j + 1 < j1; j += 2) {
        int s0 = bucket[j], s1 = bucket[j + 1];
        unsigned u0 = base[(size_t)s0 * (DIM / 2)];
        unsigned u1 = base[(size_t)s1 * (DIM / 2)];
        ax += bf_lo(u0); ay += bf_hi(u0);
        ax += bf_lo(u1); ay += bf_hi(u1);
    }
    if (j < j1) {
        unsigned u0 = base[(size_t)bucket[j] * (DIM / 2)];
        ax += bf_lo(u0); ay += bf_hi(u0);
    }
    *(float2*)(agg + (size_t)node * DIM + 2 * lane) = make_float2(ax, ay);
}

// ---------------------------------------------------------------------------
// MFMA GEMM: out[50000x128] = f( z @ W + bias ), z = scale*hin + agg (opt).
//   mfma_f32_16x16x32_bf16. Block = 4 waves; wave owns 16 rows x 128 cols
//   (8 col-tiles). W^T staged bf16 in LDS [128][136] once/block; all 32
//   B-frags hoisted to VGPRs -> zero LDS traffic in the tile loop.
//   A-frags straight from global: A[m=lane&15][k=quad*8+j] = 16 B row chunk.
//   C/D: col=lane&15, row=quad*4+reg (HW-verified mapping).
//   SPLIT: z = z_hi + z_lo bf16 decomposition (fp32-accurate agg input).
//   MODE 0: y; 1: sigmoid(y); 2: layernorm(y)*gamma+beta (fp32 out).
// In-place safe: block reads only rows it owns, stores after its loads.
// ---------------------------------------------------------------------------
template <class HinT, class HoutT, int MODE, bool HAS_AGG, bool SPLIT>
__global__ __launch_bounds__(TPB) void mfma_gemm_kernel(
    const HinT* __restrict__ hin, const float* __restrict__ agg,
    const float* __restrict__ eps_ptr, int eps_idx,
    const float* __restrict__ W, const float* __restrict__ bias,
    const float* __restrict__ gamma, const float* __restrict__ beta,
    HoutT* __restrict__ out)
{
    __shared__ short sWt[128 * 136];   // bf16 W^T, padded row: 34.8 KB

    const int tid = threadIdx.x;
    // ---- stage W^T (fp32 -> bf16, transpose) ----
    #pragma unroll
    for (int it = 0; it < 8; ++it) {
        int idx = it * 256 + tid;
        int n = idx & 127, koct = idx >> 7;   // k octet
        float f[8];
        #pragma unroll
        for (int j = 0; j < 8; ++j) f[j] = W[(8 * koct + j) * 128 + n];
        uint4 u;
        u.x = pack2bf(f[0], f[1]); u.y = pack2bf(f[2], f[3]);
        u.z = pack2bf(f[4], f[5]); u.w = pack2bf(f[6], f[7]);
        *(uint4*)&sWt[n * 136 + 8 * koct] = u;
    }
    __syncthreads();

    const int lane = tid & 63, w = tid >> 6;
    const int m = lane & 15, quad = lane >> 4;

    // ---- hoist all B-fragments: bf[c*4+k0] = W^T[16c+m][32k0+8quad ..+7] ----
    short8 bf[32];
    #pragma unroll
    for (int c = 0; c < 8; ++c)
        #pragma unroll
        for (int k0 = 0; k0 < 4; ++k0)
            bf[c * 4 + k0] = *(const short8*)&sWt[(16 * c + m) * 136 + 32 * k0 + 8 * quad];

    const float scale = HAS_AGG ? (1.0f + eps_ptr[eps_idx]) : 1.0f;

    float bias_v[8];
    #pragma unroll
    for (int c = 0; c < 8; ++c) bias_v[c] = bias[16 * c + m];
    float g_v[8], bt_v[8];
    if (MODE == 2) {
        #pragma unroll
        for (int c = 0; c < 8; ++c) { g_v[c] = gamma[16 * c + m]; bt_v[c] = beta[16 * c + m]; }
    }

    for (int t = blockIdx.x; t < NTILES; t += gridDim.x) {
        const int arow = min(t * 64 + 16 * w + m, NNODES - 1);
        const size_t rbase = (size_t)arow * DIM;

        // ---- A-fragments (global), optional agg combine + hi/lo split ----
        short8 afh[4], afl[4];
        #pragma unroll
        for (int k0 = 0; k0 < 4; ++k0) {
            const int kb = 32 * k0 + 8 * quad;
            if (!HAS_AGG && sizeof(HinT) == 2) {
                afh[k0] = *(const short8*)((const bf16_t*)hin + rbase + kb);
            } else {
                float zf[8];
                if constexpr (sizeof(HinT) == 4) {
                    float4 h0 = *(const float4*)((const float*)hin + rbase + kb);
                    float4 h1 = *(const float4*)((const float*)hin + rbase + kb + 4);
                    zf[0] = h0.x; zf[1] = h0.y; zf[2] = h0.z; zf[3] = h0.w;
                    zf[4] = h1.x; zf[5] = h1.y; zf[6] = h1.z; zf[7] = h1.w;
                } else {
                    uint4 hu = *(const uint4*)((const bf16_t*)hin + rbase + kb);
                    zf[0] = bf_lo(hu.x); zf[1] = bf_hi(hu.x);
                    zf[2] = bf_lo(hu.y); zf[3] = bf_hi(hu.y);
                    zf[4] = bf_lo(hu.z); zf[5] = bf_hi(hu.z);
                    zf[6] = bf_lo(hu.w); zf[7] = bf_hi(hu.w);
                }
                if (HAS_AGG) {
                    float4 a0 = *(const float4*)(agg + rbase + kb);
                    float4 a1 = *(const float4*)(agg + rbase + kb + 4);
                    zf[0] = fmaf(scale, zf[0], a0.x); zf[1] = fmaf(scale, zf[1], a0.y);
                    zf[2] = fmaf(scale, zf[2], a0.z); zf[3] = fmaf(scale, zf[3], a0.w);
                    zf[4] = fmaf(scale, zf[4], a1.x); zf[5] = fmaf(scale, zf[5], a1.y);
                    zf[6] = fmaf(scale, zf[6], a1.z); zf[7] = fmaf(scale, zf[7], a1.w);
                }
                S8U hi;
                hi.us[0] = pack2bf(zf[0], zf[1]); hi.us[1] = pack2bf(zf[2], zf[3]);
                hi.us[2] = pack2bf(zf[4], zf[5]); hi.us[3] = pack2bf(zf[6], zf[7]);
                afh[k0] = hi.v;
                if (SPLIT) {
                    S8U lo;
                    float r0 = zf[0] - bf_lo(hi.us[0] << 16 >> 16 ? hi.us[0] : hi.us[0]), rr;
                    // compute lo residuals explicitly
                    float l0 = zf[0] - bf_lo(hi.us[0]);
                    float l1 = zf[1] - bf_hi(hi.us[0] & 0xFFFF0000u ? hi.us[0] : hi.us[0]);
                    (void)r0; (void)rr; (void)l0; (void)l1;
                    float lw[8];
                    lw[0] = zf[0] - bf_lo(hi.us[0]); lw[1] = zf[1] - bf_hi(hi.us[0]);
                    lw[2] = zf[2] - bf_lo(hi.us[1]); lw[3] = zf[3] - bf_hi(hi.us[1]);
                    lw[4] = zf[4] - bf_lo(hi.us[2]); lw[5] = zf[5] - bf_hi(hi.us[2]);
                    lw[6] = zf[6] - bf_lo(hi.us[3]); lw[7] = zf[7] - bf_hi(hi.us[3]);
                    lo.us[0] = pack2bf(lw[0], lw[1]); lo.us[1] = pack2bf(lw[2], lw[3]);
                    lo.us[2] = pack2bf(lw[4], lw[5]); lo.us[3] = pack2bf(lw[6], lw[7]);
                    afl[k0] = lo.v;
                }
            }
        }

        // ---- MFMA ----
        f32x4 acc[8];
        #pragma unroll
        for (int c = 0; c < 8; ++c) acc[c] = (f32x4){0.f, 0.f, 0.f, 0.f};
        #pragma unroll
        for (int k0 = 0; k0 < 4; ++k0) {
            if (SPLIT) {
                #pragma unroll
                for (int c = 0; c < 8; ++c)
                    acc[c] = __builtin_amdgcn_mfma_f32_16x16x32_bf16(
                        afl[k0], bf[c * 4 + k0], acc[c], 0, 0, 0);
            }
            #pragma unroll
            for (int c = 0; c < 8; ++c)
                acc[c] = __builtin_amdgcn_mfma_f32_16x16x32_bf16(
                    afh[k0], bf[c * 4 + k0], acc[c], 0, 0, 0);
        }

        // ---- epilogue: row = t*64 + 16w + 4*quad + r, col = 16c + m ----
        const int row0 = t * 64 + 16 * w + 4 * quad;
        #pragma unroll
        for (int r = 0; r < 4; ++r) {
            const int grow = row0 + r;
            const bool ok = grow < NNODES;
            float y[8];
            #pragma unroll
            for (int c = 0; c < 8; ++c) y[c] = acc[c][r] + bias_v[c];
            if (MODE == 1) {
                #pragma unroll
                for (int c = 0; c < 8; ++c) y[c] = 1.0f / (1.0f + expf(-y[c]));
            } else if (MODE == 2) {
                float s1 = 0.f, s2 = 0.f;
                #pragma unroll
                for (int c = 0; c < 8; ++c) { s1 += y[c]; s2 = fmaf(y[c], y[c], s2); }
                #pragma unroll
                for (int d = 1; d < 16; d <<= 1) {   // reduce across 16-lane col group
                    s1 += __shfl_xor(s1, d);
                    s2 += __shfl_xor(s2, d);
                }
                float mean = s1 * (1.0f / DIM);
                float var  = s2 * (1.0f / DIM) - mean * mean;
                float rstd = rsqrtf(var + 1e-5f);
                #pragma unroll
                for (int c = 0; c < 8; ++c)
                    y[c] = fmaf((y[c] - mean) * rstd, g_v[c], bt_v[c]);
            }
            if (ok) {
                if constexpr (sizeof(HoutT) == 4) {
                    float* op = (float*)out + (size_t)grow * DIM + m;
                    #pragma unroll
                    for (int c = 0; c < 8; ++c) op[16 * c] = y[c];
                } else {
                    bf16_t* op = (bf16_t*)out + (size_t)grow * DIM + m;
                    #pragma unroll
                    for (int c = 0; c < 8; ++c) op[16 * c] = f2bf(y[c]);
                }
            }
        }
    }
}

// ---------------------------------------------------------------------------
// samples = mean + eps*std; eps = jax.random.normal(key(42)), partitionable
// threefry: block inputs (0, i), bits = out0 ^ out1, key (0,42).
// ---------------------------------------------------------------------------
__device__ __forceinline__ unsigned rotl32(unsigned x, int r) {
    return (x << r) | (x >> (32 - r));
}

__device__ __forceinline__ unsigned threefry_xor(unsigned c0, unsigned c1) {
    const unsigned k0 = 0u, k1 = 42u;
    const unsigned k2 = k0 ^ k1 ^ 0x1BD11BDAu;
    unsigned x0 = c0 + k0;
    unsigned x1 = c1 + k1;
#define TF_ROUND(R) { x0 += x1; x1 = rotl32(x1, R); x1 ^= x0; }
    TF_ROUND(13) TF_ROUND(15) TF_ROUND(26) TF_ROUND(6)
    x0 += k1; x1 += k2 + 1u;
    TF_ROUND(17) TF_ROUND(29) TF_ROUND(16) TF_ROUND(24)
    x0 += k2; x1 += k0 + 2u;
    TF_ROUND(13) TF_ROUND(15) TF_ROUND(26) TF_ROUND(6)
    x0 += k0; x1 += k1 + 3u;
    TF_ROUND(17) TF_ROUND(29) TF_ROUND(16) TF_ROUND(24)
    x0 += k1; x1 += k2 + 4u;
    TF_ROUND(13) TF_ROUND(15) TF_ROUND(26) TF_ROUND(6)
    x0 += k2; x1 += k0 + 5u;
#undef TF_ROUND
    return x0 ^ x1;
}

__device__ __forceinline__ float bits_to_normal(unsigned bits) {
    float f = __uint_as_float((bits >> 9) | 0x3F800000u) - 1.0f;
    const float lo = -0.99999994f;
    float u = __fadd_rn(__fmul_rn(f, 2.0f), lo);
    u = fmaxf(lo, u);
    float w = -log1pf(-(u * u));
    float p;
    if (w < 5.0f) {
        w -= 2.5f;
        p = 2.81022636e-08f;
        p = fmaf(p, w, 3.43273939e-07f);
        p = fmaf(p, w, -3.5233877e-06f);
        p = fmaf(p, w, -4.39150654e-06f);
        p = fmaf(p, w, 0.00021858087f);
        p = fmaf(p, w, -0.00125372503f);
        p = fmaf(p, w, -0.00417768164f);
        p = fmaf(p, w, 0.246640727f);
        p = fmaf(p, w, 1.50140941f);
    } else {
        w = sqrtf(w) - 3.0f;
        p = -0.000200214257f;
        p = fmaf(p, w, 0.000100950558f);
        p = fmaf(p, w, 0.00134934322f);
        p = fmaf(p, w, -0.00367342844f);
        p = fmaf(p, w, 0.00573950773f);
        p = fmaf(p, w, -0.0076224613f);
        p = fmaf(p, w, 0.00943887047f);
        p = fmaf(p, w, 1.00167406f);
        p = fmaf(p, w, 2.83297682f);
    }
    return 1.41421356f * (p * u);
}

__global__ __launch_bounds__(TPB) void samples_kernel(
    const float* __restrict__ mean_v, const float* __restrict__ std_v,
    float* __restrict__ samples)
{
    int t = blockIdx.x * TPB + threadIdx.x;
    if (t >= NHID / 4) return;
    float4 m = ((const float4*)mean_v)[t];
    float4 s = ((const float4*)std_v)[t];
    float e[4];
    #pragma unroll
    for (int q = 0; q < 4; q++) {
        unsigned i = 4u * (unsigned)t + (unsigned)q;
        e[q] = bits_to_normal(threefry_xor(0u, i));
    }
    float4 r;
    r.x = fmaf(e[0], s.x, m.x);
    r.y = fmaf(e[1], s.y, m.y);
    r.z = fmaf(e[2], s.z, m.z);
    r.w = fmaf(e[3], s.w, m.w);
    ((float4*)samples)[t] = r;
}

// ---------------------------------------------------------------------------
// Orchestration (same dataflow as R5):
//   S region: bf16 h during GIN, fp32 samples at the end.
//   M: p0 aggs then mean_v.  V: shared l0 agg, p1 aggs, then std_v.
//   d_ws: CSR.
// ---------------------------------------------------------------------------
extern "C" void kernel_launch(void* const* d_in, const int* in_sizes, int n_in,
                              void* d_out, int out_size, void* d_ws, size_t ws_size,
                              hipStream_t stream)
{
    const float* x     = (const float*)d_in[0];
    const int*   esrc  = (const int*)d_in[1];
    const int*   edst  = (const int*)d_in[2];
    const float* prm[2][7];
    for (int p = 0; p < 2; p++)
        for (int i = 0; i < 7; i++)
            prm[p][i] = (const float*)d_in[3 + p * 7 + i];
    const float* gamma = (const float*)d_in[17];
    const float* beta  = (const float*)d_in[18];

    float*  S  = (float*)d_out;
    bf16_t* Sb = (bf16_t*)d_out;
    float*  M  = S + NHID;
    float*  V  = M + NHID;

    int* off    = (int*)d_ws;
    int* cursor = off + (NNODES + 1);
    int* bucket = cursor + NNODES;

    const dim3 gEdge((NEDGES + TPB - 1) / TPB);
    const dim3 gGather((NNODES + (TPB / 64) - 1) / (TPB / 64));
    const dim3 gGemm(512);
    const dim3 gSamp((NHID / 4 + TPB - 1) / TPB);

    hipMemsetAsync(off, 0, (size_t)NNODES * sizeof(int), stream);
    hist_kernel<<<gEdge, TPB, 0, stream>>>(edst, off);
    scan_kernel<<<1, 1024, 0, stream>>>(off, cursor);
    bucket_kernel<<<gEdge, TPB, 0, stream>>>(esrc, edst, cursor, bucket);

    // shared layer-0 aggregation
    gather_agg_f32_kernel<<<gGather, TPB, 0, stream>>>(x, off, bucket, V);

    for (int p = 0; p < 2; p++) {
        const float* W1  = prm[p][0];
        const float* b1  = prm[p][1];
        const float* W2  = prm[p][2];
        const float* b2  = prm[p][3];
        const float* eps = prm[p][4];
        const float* Wo  = prm[p][5];
        const float* bo  = prm[p][6];
        float* AGG = (p == 0) ? M : V;
        float* OUT = (p == 0) ? M : V;

        // layer 0: fp32 x + shared agg (V), sigmoid, -> bf16 h
        mfma_gemm_kernel<float, bf16_t, 1, true, true><<<gGemm, TPB, 0, stream>>>(
            x, V, eps, 0, W1, b1, nullptr, nullptr, Sb);
        mfma_gemm_kernel<bf16_t, bf16_t, 0, false, false><<<gGemm, TPB, 0, stream>>>(
            Sb, nullptr, nullptr, 0, W2, b2, nullptr, nullptr, Sb);

        for (int l = 1; l < 3; l++) {
            gather_agg_bf16_kernel<<<gGather, TPB, 0, stream>>>(Sb, off, bucket, AGG);
            mfma_gemm_kernel<bf16_t, bf16_t, 1, true, true><<<gGemm, TPB, 0, stream>>>(
                Sb, AGG, eps, l, W1 + (size_t)l * DIM * DIM, b1 + l * DIM,
                nullptr, nullptr, Sb);
            mfma_gemm_kernel<bf16_t, bf16_t, 0, false, false><<<gGemm, TPB, 0, stream>>>(
                Sb, nullptr, nullptr, 0, W2 + (size_t)l * DIM * DIM, b2 + l * DIM,
                nullptr, nullptr, Sb);
        }

        mfma_gemm_kernel<bf16_t, float, 2, false, false><<<gGemm, TPB, 0, stream>>>(
            Sb, nullptr, nullptr, 0, Wo, bo, gamma, beta, OUT);
    }

    samples_kernel<<<gSamp, TPB, 0, stream>>>(M, V, S);
}